// Round 6
// baseline (10909.052 us; speedup 1.0000x reference)
//
#include <hip/hip_runtime.h>
#include <hip/hip_bf16.h>

// Problem constants
#define B_ROWS 16384
#define OBS_D  512
#define H_D    1024
#define N_AG   9

typedef __attribute__((ext_vector_type(8))) short short8;
typedef __attribute__((ext_vector_type(4))) float floatx4;

__device__ __forceinline__ unsigned short f_to_bf_raw(float f) {
  union { float f; unsigned u; } c; c.f = f;
  unsigned u = c.u;
  u = u + 0x7FFF + ((u >> 16) & 1);   // round-to-nearest-even
  return (unsigned short)(u >> 16);
}

// ---------------------------------------------------------------------------
// Mega-prep: obs cast, W1T, W2T, WH (heads weights fused + Wk1 fold),
// bias2048/w2cat concat. Branch is block-uniform.
// Grid: [0,4096) obs | [4096,4608) W1T | [4608,5632) W2T |
//       [5632,7680) WH | [7680,7688) vecs
// ---------------------------------------------------------------------------
__global__ __launch_bounds__(256) void prep_all(
    const float* __restrict__ obs,
    const float* __restrict__ W1, const float* __restrict__ W2,
    const float* __restrict__ Wc1, const float* __restrict__ Wt1,
    const float* __restrict__ Wk1,
    const float* __restrict__ bc1, const float* __restrict__ bt1,
    const float* __restrict__ bk1,
    const float* __restrict__ Wc2, const float* __restrict__ Wt2,
    const float* __restrict__ Wk2,
    unsigned short* __restrict__ obs_bf,
    unsigned short* __restrict__ W1T, unsigned short* __restrict__ W2T,
    unsigned short* __restrict__ WH,
    float* __restrict__ bias2048, float* __restrict__ w2cat) {
  __shared__ float t[32][33];
  const int bx  = blockIdx.x;
  const int tid = threadIdx.x;

  if (bx < 4096) {                       // obs fp32 -> bf16, 8 elems/thread
    int i = (bx * 256 + tid) * 8;
    float4 a = *(const float4*)(obs + i);
    float4 b = *(const float4*)(obs + i + 4);
    short8 o;
    o[0] = (short)f_to_bf_raw(a.x); o[1] = (short)f_to_bf_raw(a.y);
    o[2] = (short)f_to_bf_raw(a.z); o[3] = (short)f_to_bf_raw(a.w);
    o[4] = (short)f_to_bf_raw(b.x); o[5] = (short)f_to_bf_raw(b.y);
    o[6] = (short)f_to_bf_raw(b.z); o[7] = (short)f_to_bf_raw(b.w);
    *(short8*)(obs_bf + i) = o;
    return;
  }

  const int tx = tid & 31;
  const int ty = tid >> 5;   // 0..7

  if (bx < 4608) {                       // W1 [512,1024] -> W1T [1024,512]
    const int tt = bx - 4096;
    const int k0 = (tt & 15) * 32;
    const int n0 = (tt >> 4) * 32;
#pragma unroll
    for (int i = ty; i < 32; i += 8)
      t[i][tx] = W1[(size_t)(k0 + i) * 1024 + n0 + tx];
    __syncthreads();
#pragma unroll
    for (int i = ty; i < 32; i += 8)
      W1T[(size_t)(n0 + i) * 512 + k0 + tx] = f_to_bf_raw(t[tx][i]);
    return;
  }

  if (bx < 5632) {                       // W2 [1024,1024] -> W2T [1024,1024]
    const int tt = bx - 4608;
    const int k0 = (tt & 31) * 32;
    const int n0 = (tt >> 5) * 32;
#pragma unroll
    for (int i = ty; i < 32; i += 8)
      t[i][tx] = W2[(size_t)(k0 + i) * 1024 + n0 + tx];
    __syncthreads();
#pragma unroll
    for (int i = ty; i < 32; i += 8)
      W2T[(size_t)(n0 + i) * 1024 + k0 + tx] = f_to_bf_raw(t[tx][i]);
    return;
  }

  if (bx < 7680) {                       // WH [2048,1024] (Wc1|Wt1|Wk1-fold)^T
    const int tt = bx - 5632;
    const int k0 = (tt & 31) * 32;
    const int n0 = (tt >> 5) * 32;       // region-uniform per block
#pragma unroll
    for (int i = ty; i < 32; i += 8) {
      const int n = n0 + tx;
      float v;
      if (n0 < 512)
        v = Wc1[(size_t)(k0 + i) * 512 + n];
      else if (n0 < 1024)
        v = Wt1[(size_t)(k0 + i) * 512 + (n - 512)];
      else
        v = Wk1[(size_t)(k0 + i) * 1024 + (n - 1024)]
          + Wk1[(size_t)(k0 + i + 1024) * 1024 + (n - 1024)];
      t[i][tx] = v;
    }
    __syncthreads();
#pragma unroll
    for (int i = ty; i < 32; i += 8)
      WH[(size_t)(n0 + i) * 1024 + k0 + tx] = f_to_bf_raw(t[tx][i]);
    return;
  }

  {                                      // bias2048 / w2cat
    int n = (bx - 7680) * 256 + tid;
    float b, w;
    if (n < 512)       { b = bc1[n];        w = Wc2[n]; }
    else if (n < 1024) { b = bt1[n - 512];  w = Wt2[n - 512]; }
    else               { b = bk1[n - 1024]; w = Wk2[n - 1024]; }
    bias2048[n] = b;
    w2cat[n] = w;
  }
}

// ===========================================================================
// GEMM core v5: 128x128 tile, BK=32, LDS double-buffer (2 x 16 KB) PLUS
// REGISTER double-buffer of MFMA fragments, one barrier per K-iter:
//   prologue: DMA(0)->buf0; sync; DMA(1)->buf1; ds_read frags(0)->F[0]
//   iter k:   sync            (drains DMA(k+1); all waves hold frags(k) in
//                              regs, so buf[k&1] is dead)
//             DMA(k+2) -> buf[k&1]
//             ds_read frags(k+1) -> F[other]   (no consumer this iter!)
//             16 x MFMA on F[cur]              (zero dependence on the reads)
// MFMAs are issue-ready at the top of every iteration; ds_read latency hides
// behind them; DMA gets a full compute phase + barrier in flight.
// Swizzle (64B rows): 16B-chunk c stored at c ^ ((row>>1)&3) -> conflict-free
// (2 lanes/bank, free per m136); applied on global src so DMA dest stays
// wave-uniform + lane*16. K % 64 == 0 (512 / 1024 here).
// ===========================================================================
#define GEMM_CORE_V5(ACC_DECL)                                                 \
  __shared__ __align__(16) unsigned short As[2][128 * 32];                     \
  __shared__ __align__(16) unsigned short Bs[2][128 * 32];                     \
  const int tid  = threadIdx.x;                                                \
  const int lane = tid & 63;                                                   \
  const int wave = tid >> 6;                                                   \
  const int m0 = blockIdx.x * 128;                                             \
  const int n0 = blockIdx.y * 128;                                             \
  const int wm = (wave & 1) * 64;                                              \
  const int wn = (wave >> 1) * 64;                                             \
  const int fr = lane & 15;                                                    \
  const int fq = lane >> 4;                                                    \
  ACC_DECL;                                                                    \
  const size_t rowb = (size_t)K * 2;                                           \
  const int srow   = lane >> 2;                                                \
  const int schunk = (lane & 3) ^ ((srow >> 1) & 3);                           \
  const char* gA0 = (const char*)A + (size_t)(m0 + wave * 32 + srow) * rowb    \
                    + schunk * 16;                                             \
  const char* gA1 = gA0 + 16 * rowb;                                           \
  const char* gB0 = (const char*)Bt + (size_t)(n0 + wave * 32 + srow) * rowb   \
                    + schunk * 16;                                             \
  const char* gB1 = gB0 + 16 * rowb;                                           \
  char* lA = (char*)&As[0][0] + (wave * 32) * 64 + lane * 16;                  \
  char* lB = (char*)&Bs[0][0] + (wave * 32) * 64 + lane * 16;                  \
  const int fswz = (fr >> 1) & 3;                                              \
  const int fsA = (wm + fr) * 64 + ((fq ^ fswz) * 16);                         \
  const int fsB = (wn + fr) * 64 + ((fq ^ fswz) * 16);                         \
  const int nIter = K >> 5;                                                    \
  /* prologue: tile0 -> buf0, tile1 -> buf1, frags(0) -> F[0] */               \
  __builtin_amdgcn_global_load_lds(                                            \
      (const __attribute__((address_space(1))) void*)gA0,                      \
      (__attribute__((address_space(3))) void*)lA, 16, 0, 0);                  \
  __builtin_amdgcn_global_load_lds(                                            \
      (const __attribute__((address_space(1))) void*)gA1,                      \
      (__attribute__((address_space(3))) void*)(lA + 1024), 16, 0, 0);         \
  __builtin_amdgcn_global_load_lds(                                            \
      (const __attribute__((address_space(1))) void*)gB0,                      \
      (__attribute__((address_space(3))) void*)lB, 16, 0, 0);                  \
  __builtin_amdgcn_global_load_lds(                                            \
      (const __attribute__((address_space(1))) void*)gB1,                      \
      (__attribute__((address_space(3))) void*)(lB + 1024), 16, 0, 0);         \
  gA0 += 64; gA1 += 64; gB0 += 64; gB1 += 64;                                  \
  __syncthreads();                                                             \
  __builtin_amdgcn_global_load_lds(                                            \
      (const __attribute__((address_space(1))) void*)gA0,                      \
      (__attribute__((address_space(3))) void*)(lA + 8192), 16, 0, 0);         \
  __builtin_amdgcn_global_load_lds(                                            \
      (const __attribute__((address_space(1))) void*)gA1,                      \
      (__attribute__((address_space(3))) void*)(lA + 9216), 16, 0, 0);         \
  __builtin_amdgcn_global_load_lds(                                            \
      (const __attribute__((address_space(1))) void*)gB0,                      \
      (__attribute__((address_space(3))) void*)(lB + 8192), 16, 0, 0);         \
  __builtin_amdgcn_global_load_lds(                                            \
      (const __attribute__((address_space(1))) void*)gB1,                      \
      (__attribute__((address_space(3))) void*)(lB + 9216), 16, 0, 0);         \
  gA0 += 64; gA1 += 64; gB0 += 64; gB1 += 64;                                  \
  short8 Fa[2][4], Fb[2][4];                                                   \
  _Pragma("unroll")                                                            \
  for (int mi = 0; mi < 4; ++mi)                                               \
    Fa[0][mi] = *(const short8*)((const char*)&As[0][0] + fsA + mi * 1024);    \
  _Pragma("unroll")                                                            \
  for (int ni = 0; ni < 4; ++ni)                                               \
    Fb[0][ni] = *(const short8*)((const char*)&Bs[0][0] + fsB + ni * 1024);    \
  _Pragma("unroll 2")                                                          \
  for (int k = 0; k < nIter; ++k) {                                            \
    const int cur = k & 1;                                                     \
    __syncthreads();                                                           \
    if (k + 2 < nIter) {                                                       \
      char* dA = lA + cur * 8192;                                              \
      char* dB = lB + cur * 8192;                                              \
      __builtin_amdgcn_global_load_lds(                                        \
          (const __attribute__((address_space(1))) void*)gA0,                  \
          (__attribute__((address_space(3))) void*)dA, 16, 0, 0);              \
      __builtin_amdgcn_global_load_lds(                                        \
          (const __attribute__((address_space(1))) void*)gA1,                  \
          (__attribute__((address_space(3))) void*)(dA + 1024), 16, 0, 0);     \
      __builtin_amdgcn_global_load_lds(                                        \
          (const __attribute__((address_space(1))) void*)gB0,                  \
          (__attribute__((address_space(3))) void*)dB, 16, 0, 0);              \
      __builtin_amdgcn_global_load_lds(                                        \
          (const __attribute__((address_space(1))) void*)gB1,                  \
          (__attribute__((address_space(3))) void*)(dB + 1024), 16, 0, 0);     \
      gA0 += 64; gA1 += 64; gB0 += 64; gB1 += 64;                              \
    }                                                                          \
    if (k + 1 < nIter) {                                                       \
      const char* bAs = (const char*)&As[0][0] + (cur ^ 1) * 8192;             \
      const char* bBs = (const char*)&Bs[0][0] + (cur ^ 1) * 8192;             \
      _Pragma("unroll")                                                        \
      for (int mi = 0; mi < 4; ++mi)                                           \
        Fa[cur ^ 1][mi] = *(const short8*)(bAs + fsA + mi * 1024);             \
      _Pragma("unroll")                                                        \
      for (int ni = 0; ni < 4; ++ni)                                           \
        Fb[cur ^ 1][ni] = *(const short8*)(bBs + fsB + ni * 1024);             \
    }                                                                          \
    _Pragma("unroll")                                                          \
    for (int mi = 0; mi < 4; ++mi)                                             \
      _Pragma("unroll")                                                        \
      for (int ni = 0; ni < 4; ++ni)                                           \
        acc[mi][ni] = __builtin_amdgcn_mfma_f32_16x16x32_bf16(                 \
            Fa[cur][mi], Fb[cur][ni], acc[mi][ni], 0, 0, 0);                   \
  }

#define ACC_INIT                                                               \
  floatx4 acc[4][4];                                                           \
  _Pragma("unroll")                                                            \
  for (int i = 0; i < 4; ++i)                                                  \
    _Pragma("unroll")                                                          \
    for (int j = 0; j < 4; ++j) acc[i][j] = (floatx4){0.f, 0.f, 0.f, 0.f}

// ---------------------------------------------------------------------------
// GEMM: C = relu(A @ Bt^T + bias), bf16 out
// ---------------------------------------------------------------------------
__global__ __launch_bounds__(256, 3) void gemm_bias_relu(
    const unsigned short* __restrict__ A,
    const unsigned short* __restrict__ Bt,
    const float* __restrict__ bias,
    unsigned short* __restrict__ C,
    int M, int N, int K) {
  GEMM_CORE_V5(ACC_INIT)

  // Epilogue: C/D layout col=lane&15, row=(lane>>4)*4+reg
#pragma unroll
  for (int ni = 0; ni < 4; ++ni) {
    const int gn = n0 + wn + ni * 16 + fr;
    const float bv = bias[gn];
#pragma unroll
    for (int mi = 0; mi < 4; ++mi) {
#pragma unroll
      for (int r = 0; r < 4; ++r) {
        const int gm = m0 + wm + mi * 16 + fq * 4 + r;
        float v = acc[mi][ni][r] + bv;
        v = v > 0.f ? v : 0.f;
        C[(size_t)gm * N + gn] = f_to_bf_raw(v);
      }
    }
  }
}

// ---------------------------------------------------------------------------
// Fused heads GEMM: relu(G @ WH^T + bias2048) dotted with w2cat in-register,
// non-atomic partials part[j][row], j = blockIdx.y*2 + wave_half in [0,32).
// j 0..7 coverage, 8..15 tracking, 16..31 cooperation.
// ---------------------------------------------------------------------------
__global__ __launch_bounds__(256, 3) void gemm_heads_fused(
    const unsigned short* __restrict__ A,    // G [B,1024]
    const unsigned short* __restrict__ Bt,   // WH [2048,1024]
    const float* __restrict__ bias,          // bias2048
    const float* __restrict__ w2,            // w2cat
    float* __restrict__ part,                // [32][B_ROWS]
    int M, int N, int K) {
  GEMM_CORE_V5(ACC_INIT)

  const int j = blockIdx.y * 2 + (wave >> 1);
  float w2v[4], bv[4];
#pragma unroll
  for (int ni = 0; ni < 4; ++ni) {
    const int gn = n0 + wn + ni * 16 + fr;
    w2v[ni] = w2[gn];
    bv[ni]  = bias[gn];
  }
#pragma unroll
  for (int mi = 0; mi < 4; ++mi) {
#pragma unroll
    for (int r = 0; r < 4; ++r) {
      float p = 0.f;
#pragma unroll
      for (int ni = 0; ni < 4; ++ni) {
        float v = acc[mi][ni][r] + bv[ni];
        v = v > 0.f ? v : 0.f;
        p += v * w2v[ni];
      }
      p += __shfl_xor(p, 1);
      p += __shfl_xor(p, 2);
      p += __shfl_xor(p, 4);
      p += __shfl_xor(p, 8);
      if (fr == 0) {
        const int gm = m0 + wm + mi * 16 + fq * 4 + r;
        part[(size_t)j * B_ROWS + gm] = p;
      }
    }
  }
}

// ---------------------------------------------------------------------------
// Final: sum partials, sigmoid, broadcast to out [3, B, 9]. 1 thread/row.
// ---------------------------------------------------------------------------
__global__ __launch_bounds__(256) void final_out(
    const float* __restrict__ part,
    const float* __restrict__ bc2, const float* __restrict__ bt2,
    const float* __restrict__ bk2, float* __restrict__ out) {
  const int row = blockIdx.x * 256 + threadIdx.x;
  float sc = 0.f, st = 0.f, sk = 0.f;
#pragma unroll
  for (int j = 0; j < 8; ++j)  sc += part[(size_t)j * B_ROWS + row];
#pragma unroll
  for (int j = 8; j < 16; ++j) st += part[(size_t)j * B_ROWS + row];
#pragma unroll
  for (int j = 16; j < 32; ++j) sk += part[(size_t)j * B_ROWS + row];
  const float cv = 1.f / (1.f + expf(-(sc + bc2[0])));
  const float tv = 1.f / (1.f + expf(-(st + bt2[0])));
  const float kv = 1.f / (1.f + expf(-(sk + bk2[0])));
  float* o0 = out + (size_t)row * N_AG;
  float* o1 = out + (size_t)(B_ROWS + row) * N_AG;
  float* o2 = out + (size_t)(2 * B_ROWS + row) * N_AG;
#pragma unroll
  for (int a = 0; a < N_AG; ++a) { o0[a] = cv; o1[a] = tv; o2[a] = kv; }
}

// ---------------------------------------------------------------------------
extern "C" void kernel_launch(void* const* d_in, const int* in_sizes, int n_in,
                              void* d_out, int out_size, void* d_ws, size_t ws_size,
                              hipStream_t stream) {
  const float* obs = (const float*)d_in[0];
  // d_in[1] agent_positions: unused (outputs don't depend on it)
  const float* W1  = (const float*)d_in[2];
  const float* b1  = (const float*)d_in[3];
  const float* W2  = (const float*)d_in[4];
  const float* b2  = (const float*)d_in[5];
  const float* Wc1 = (const float*)d_in[6];
  const float* bc1 = (const float*)d_in[7];
  const float* Wc2 = (const float*)d_in[8];
  const float* bc2 = (const float*)d_in[9];
  const float* Wt1 = (const float*)d_in[10];
  const float* bt1 = (const float*)d_in[11];
  const float* Wt2 = (const float*)d_in[12];
  const float* bt2 = (const float*)d_in[13];
  const float* Wk1 = (const float*)d_in[14];
  const float* bk1 = (const float*)d_in[15];
  const float* Wk2 = (const float*)d_in[16];
  const float* bk2 = (const float*)d_in[17];
  float* out = (float*)d_out;

  // Workspace layout. PART aliases obs_bf (disjoint lifetimes).
  char* ws = (char*)d_ws;
  unsigned short* obs_bf  = (unsigned short*)(ws + 0);         // 16 MB
  float*          PART    = (float*)(ws + 0);                  // 2 MB (alias)
  unsigned short* W1T     = (unsigned short*)(ws + 16777216);  // 1 MB  [1024,512]
  unsigned short* W2T     = (unsigned short*)(ws + 17825792);  // 2 MB  [1024,1024]
  unsigned short* WH      = (unsigned short*)(ws + 19922944);  // 4 MB  [2048,1024]
  float*          bias2048= (float*)(ws + 24117248);           // 8 KB
  float*          w2cat   = (float*)(ws + 24125440);           // 8 KB
  unsigned short* G1      = (unsigned short*)(ws + 24330240);  // 32 MB
  unsigned short* G       = (unsigned short*)(ws + 57884672);  // 32 MB

  prep_all<<<7688, 256, 0, stream>>>(obs, W1, W2, Wc1, Wt1, Wk1,
                                     bc1, bt1, bk1, Wc2, Wt2, Wk2,
                                     obs_bf, W1T, W2T, WH, bias2048, w2cat);

  gemm_bias_relu<<<dim3(128, 8), 256, 0, stream>>>(obs_bf, W1T, b1, G1, B_ROWS, 1024, 512);
  gemm_bias_relu<<<dim3(128, 8), 256, 0, stream>>>(G1, W2T, b2, G, B_ROWS, 1024, 1024);

  gemm_heads_fused<<<dim3(128, 16), 256, 0, stream>>>(G, WH, bias2048, w2cat, PART,
                                                      B_ROWS, 2048, 1024);

  final_out<<<B_ROWS / 256, 256, 0, stream>>>(PART, bc2, bt2, bk2, out);
}

// Round 7
// 294.446 us; speedup vs baseline: 37.0494x; 37.0494x over previous
//
#include <hip/hip_runtime.h>
#include <hip/hip_bf16.h>

// Problem constants
#define B_ROWS 16384
#define OBS_D  512
#define H_D    1024
#define N_AG   9

typedef __attribute__((ext_vector_type(8))) short short8;
typedef __attribute__((ext_vector_type(4))) float floatx4;

__device__ __forceinline__ unsigned short f_to_bf_raw(float f) {
  union { float f; unsigned u; } c; c.f = f;
  unsigned u = c.u;
  u = u + 0x7FFF + ((u >> 16) & 1);   // round-to-nearest-even
  return (unsigned short)(u >> 16);
}

// ---------------------------------------------------------------------------
// Mega-prep: obs cast, W1T, W2T, WH (heads weights fused + Wk1 fold),
// bias2048/w2cat concat. Branch is block-uniform.
// Grid: [0,4096) obs | [4096,4608) W1T | [4608,5632) W2T |
//       [5632,7680) WH | [7680,7688) vecs
// ---------------------------------------------------------------------------
__global__ __launch_bounds__(256) void prep_all(
    const float* __restrict__ obs,
    const float* __restrict__ W1, const float* __restrict__ W2,
    const float* __restrict__ Wc1, const float* __restrict__ Wt1,
    const float* __restrict__ Wk1,
    const float* __restrict__ bc1, const float* __restrict__ bt1,
    const float* __restrict__ bk1,
    const float* __restrict__ Wc2, const float* __restrict__ Wt2,
    const float* __restrict__ Wk2,
    unsigned short* __restrict__ obs_bf,
    unsigned short* __restrict__ W1T, unsigned short* __restrict__ W2T,
    unsigned short* __restrict__ WH,
    float* __restrict__ bias2048, float* __restrict__ w2cat) {
  __shared__ float t[32][33];
  const int bx  = blockIdx.x;
  const int tid = threadIdx.x;

  if (bx < 4096) {                       // obs fp32 -> bf16, 8 elems/thread
    int i = (bx * 256 + tid) * 8;
    float4 a = *(const float4*)(obs + i);
    float4 b = *(const float4*)(obs + i + 4);
    short8 o;
    o[0] = (short)f_to_bf_raw(a.x); o[1] = (short)f_to_bf_raw(a.y);
    o[2] = (short)f_to_bf_raw(a.z); o[3] = (short)f_to_bf_raw(a.w);
    o[4] = (short)f_to_bf_raw(b.x); o[5] = (short)f_to_bf_raw(b.y);
    o[6] = (short)f_to_bf_raw(b.z); o[7] = (short)f_to_bf_raw(b.w);
    *(short8*)(obs_bf + i) = o;
    return;
  }

  const int tx = tid & 31;
  const int ty = tid >> 5;   // 0..7

  if (bx < 4608) {                       // W1 [512,1024] -> W1T [1024,512]
    const int tt = bx - 4096;
    const int k0 = (tt & 15) * 32;
    const int n0 = (tt >> 4) * 32;
#pragma unroll
    for (int i = ty; i < 32; i += 8)
      t[i][tx] = W1[(size_t)(k0 + i) * 1024 + n0 + tx];
    __syncthreads();
#pragma unroll
    for (int i = ty; i < 32; i += 8)
      W1T[(size_t)(n0 + i) * 512 + k0 + tx] = f_to_bf_raw(t[tx][i]);
    return;
  }

  if (bx < 5632) {                       // W2 [1024,1024] -> W2T [1024,1024]
    const int tt = bx - 4608;
    const int k0 = (tt & 31) * 32;
    const int n0 = (tt >> 5) * 32;
#pragma unroll
    for (int i = ty; i < 32; i += 8)
      t[i][tx] = W2[(size_t)(k0 + i) * 1024 + n0 + tx];
    __syncthreads();
#pragma unroll
    for (int i = ty; i < 32; i += 8)
      W2T[(size_t)(n0 + i) * 1024 + k0 + tx] = f_to_bf_raw(t[tx][i]);
    return;
  }

  if (bx < 7680) {                       // WH [2048,1024] (Wc1|Wt1|Wk1-fold)^T
    const int tt = bx - 5632;
    const int k0 = (tt & 31) * 32;
    const int n0 = (tt >> 5) * 32;       // region-uniform per block
#pragma unroll
    for (int i = ty; i < 32; i += 8) {
      const int n = n0 + tx;
      float v;
      if (n0 < 512)
        v = Wc1[(size_t)(k0 + i) * 512 + n];
      else if (n0 < 1024)
        v = Wt1[(size_t)(k0 + i) * 512 + (n - 512)];
      else
        v = Wk1[(size_t)(k0 + i) * 1024 + (n - 1024)]
          + Wk1[(size_t)(k0 + i + 1024) * 1024 + (n - 1024)];
      t[i][tx] = v;
    }
    __syncthreads();
#pragma unroll
    for (int i = ty; i < 32; i += 8)
      WH[(size_t)(n0 + i) * 1024 + k0 + tx] = f_to_bf_raw(t[tx][i]);
    return;
  }

  {                                      // bias2048 / w2cat
    int n = (bx - 7680) * 256 + tid;
    float b, w;
    if (n < 512)       { b = bc1[n];        w = Wc2[n]; }
    else if (n < 1024) { b = bt1[n - 512];  w = Wt2[n - 512]; }
    else               { b = bk1[n - 1024]; w = Wk2[n - 1024]; }
    bias2048[n] = b;
    w2cat[n] = w;
  }
}

// ===========================================================================
// GEMM core v6: identical pipeline to v5 (LDS dbuf + REGISTER dbuf, one
// barrier per K-iter) but K is a TEMPLATE CONSTANT so nIter is constexpr,
// the K-loop FULLY UNROLLS, and Fa[cur]/Fb[cur] indices are compile-time
// -> fragments live in VGPRs. (Round-6 lesson: runtime-indexed arrays get
// demoted to scratch — WRITE_SIZE exploded to 1 GB, MfmaUtil 0.5%.)
//   iter k: sync                (drains DMA(k+1); frags(k) already in regs)
//           DMA(k+2) -> buf[k&1]
//           ds_read frags(k+1) -> F[(k+1)&1]   (no consumer this iter)
//           16 x MFMA on F[k&1]                (issue-ready immediately)
// Swizzle (64B rows): 16B-chunk c stored at c ^ ((row>>1)&3) -> 2 lanes/bank
// (free, m136); applied on global src so DMA dest stays wave-uniform+lane*16.
// ===========================================================================
#define GLD_LDS(gp, lp)                                                        \
  __builtin_amdgcn_global_load_lds(                                            \
      (const __attribute__((address_space(1))) void*)(gp),                     \
      (__attribute__((address_space(3))) void*)(lp), 16, 0, 0)

#define GEMM_CORE_V6(ACC_DECL)                                                 \
  __shared__ __align__(16) unsigned short As[2][128 * 32];                     \
  __shared__ __align__(16) unsigned short Bs[2][128 * 32];                     \
  const int tid  = threadIdx.x;                                                \
  const int lane = tid & 63;                                                   \
  const int wave = tid >> 6;                                                   \
  const int m0 = blockIdx.x * 128;                                             \
  const int n0 = blockIdx.y * 128;                                             \
  const int wm = (wave & 1) * 64;                                              \
  const int wn = (wave >> 1) * 64;                                             \
  const int fr = lane & 15;                                                    \
  const int fq = lane >> 4;                                                    \
  ACC_DECL;                                                                    \
  const size_t rowb = (size_t)K * 2;                                           \
  const int srow   = lane >> 2;                                                \
  const int schunk = (lane & 3) ^ ((srow >> 1) & 3);                           \
  const char* gA0 = (const char*)A + (size_t)(m0 + wave * 32 + srow) * rowb    \
                    + schunk * 16;                                             \
  const char* gA1 = gA0 + 16 * rowb;                                           \
  const char* gB0 = (const char*)Bt + (size_t)(n0 + wave * 32 + srow) * rowb   \
                    + schunk * 16;                                             \
  const char* gB1 = gB0 + 16 * rowb;                                           \
  char* lA = (char*)&As[0][0] + (wave * 32) * 64 + lane * 16;                  \
  char* lB = (char*)&Bs[0][0] + (wave * 32) * 64 + lane * 16;                  \
  const int fswz = (fr >> 1) & 3;                                              \
  const int fsA = (wm + fr) * 64 + ((fq ^ fswz) * 16);                         \
  const int fsB = (wn + fr) * 64 + ((fq ^ fswz) * 16);                         \
  constexpr int nIter = K >> 5;                                                \
  /* prologue: tile0 -> buf0; sync; tile1 -> buf1; frags(0) -> F[0] */         \
  GLD_LDS(gA0, lA);        GLD_LDS(gA1, lA + 1024);                            \
  GLD_LDS(gB0, lB);        GLD_LDS(gB1, lB + 1024);                            \
  gA0 += 64; gA1 += 64; gB0 += 64; gB1 += 64;                                  \
  __syncthreads();                                                             \
  GLD_LDS(gA0, lA + 8192); GLD_LDS(gA1, lA + 9216);                            \
  GLD_LDS(gB0, lB + 8192); GLD_LDS(gB1, lB + 9216);                            \
  gA0 += 64; gA1 += 64; gB0 += 64; gB1 += 64;                                  \
  short8 Fa[2][4], Fb[2][4];                                                   \
  _Pragma("unroll")                                                            \
  for (int mi = 0; mi < 4; ++mi)                                               \
    Fa[0][mi] = *(const short8*)((const char*)&As[0][0] + fsA + mi * 1024);    \
  _Pragma("unroll")                                                            \
  for (int ni = 0; ni < 4; ++ni)                                               \
    Fb[0][ni] = *(const short8*)((const char*)&Bs[0][0] + fsB + ni * 1024);    \
  _Pragma("unroll")                                                            \
  for (int k = 0; k < nIter; ++k) {      /* constexpr bound -> full unroll */  \
    const int cur = k & 1;               /* constant per unrolled body */      \
    __syncthreads();                                                           \
    if (k + 2 < nIter) {                                                       \
      char* dA = lA + cur * 8192;                                              \
      char* dB = lB + cur * 8192;                                              \
      GLD_LDS(gA0, dA); GLD_LDS(gA1, dA + 1024);                               \
      GLD_LDS(gB0, dB); GLD_LDS(gB1, dB + 1024);                               \
      gA0 += 64; gA1 += 64; gB0 += 64; gB1 += 64;                              \
    }                                                                          \
    if (k + 1 < nIter) {                                                       \
      const char* bAs = (const char*)&As[0][0] + (cur ^ 1) * 8192;             \
      const char* bBs = (const char*)&Bs[0][0] + (cur ^ 1) * 8192;             \
      _Pragma("unroll")                                                        \
      for (int mi = 0; mi < 4; ++mi)                                           \
        Fa[cur ^ 1][mi] = *(const short8*)(bAs + fsA + mi * 1024);             \
      _Pragma("unroll")                                                        \
      for (int ni = 0; ni < 4; ++ni)                                           \
        Fb[cur ^ 1][ni] = *(const short8*)(bBs + fsB + ni * 1024);             \
    }                                                                          \
    _Pragma("unroll")                                                          \
    for (int mi = 0; mi < 4; ++mi)                                             \
      _Pragma("unroll")                                                        \
      for (int ni = 0; ni < 4; ++ni)                                           \
        acc[mi][ni] = __builtin_amdgcn_mfma_f32_16x16x32_bf16(                 \
            Fa[cur][mi], Fb[cur][ni], acc[mi][ni], 0, 0, 0);                   \
  }

#define ACC_INIT                                                               \
  floatx4 acc[4][4];                                                           \
  _Pragma("unroll")                                                            \
  for (int i = 0; i < 4; ++i)                                                  \
    _Pragma("unroll")                                                          \
    for (int j = 0; j < 4; ++j) acc[i][j] = (floatx4){0.f, 0.f, 0.f, 0.f}

// ---------------------------------------------------------------------------
// GEMM: C = relu(A @ Bt^T + bias), bf16 out. K is a template constant.
// ---------------------------------------------------------------------------
template <int K>
__global__ __launch_bounds__(256, 3) void gemm_bias_relu(
    const unsigned short* __restrict__ A,
    const unsigned short* __restrict__ Bt,
    const float* __restrict__ bias,
    unsigned short* __restrict__ C,
    int M, int N) {
  GEMM_CORE_V6(ACC_INIT)

  // Epilogue: C/D layout col=lane&15, row=(lane>>4)*4+reg
#pragma unroll
  for (int ni = 0; ni < 4; ++ni) {
    const int gn = n0 + wn + ni * 16 + fr;
    const float bv = bias[gn];
#pragma unroll
    for (int mi = 0; mi < 4; ++mi) {
#pragma unroll
      for (int r = 0; r < 4; ++r) {
        const int gm = m0 + wm + mi * 16 + fq * 4 + r;
        float v = acc[mi][ni][r] + bv;
        v = v > 0.f ? v : 0.f;
        C[(size_t)gm * N + gn] = f_to_bf_raw(v);
      }
    }
  }
}

// ---------------------------------------------------------------------------
// Fused heads GEMM: relu(G @ WH^T + bias2048) dotted with w2cat in-register,
// non-atomic partials part[j][row], j = blockIdx.y*2 + wave_half in [0,32).
// j 0..7 coverage, 8..15 tracking, 16..31 cooperation.
// ---------------------------------------------------------------------------
template <int K>
__global__ __launch_bounds__(256, 3) void gemm_heads_fused(
    const unsigned short* __restrict__ A,    // G [B,1024]
    const unsigned short* __restrict__ Bt,   // WH [2048,1024]
    const float* __restrict__ bias,          // bias2048
    const float* __restrict__ w2,            // w2cat
    float* __restrict__ part,                // [32][B_ROWS]
    int M, int N) {
  GEMM_CORE_V6(ACC_INIT)

  const int j = blockIdx.y * 2 + (wave >> 1);
  float w2v[4], bv[4];
#pragma unroll
  for (int ni = 0; ni < 4; ++ni) {
    const int gn = n0 + wn + ni * 16 + fr;
    w2v[ni] = w2[gn];
    bv[ni]  = bias[gn];
  }
#pragma unroll
  for (int mi = 0; mi < 4; ++mi) {
#pragma unroll
    for (int r = 0; r < 4; ++r) {
      float p = 0.f;
#pragma unroll
      for (int ni = 0; ni < 4; ++ni) {
        float v = acc[mi][ni][r] + bv[ni];
        v = v > 0.f ? v : 0.f;
        p += v * w2v[ni];
      }
      p += __shfl_xor(p, 1);
      p += __shfl_xor(p, 2);
      p += __shfl_xor(p, 4);
      p += __shfl_xor(p, 8);
      if (fr == 0) {
        const int gm = m0 + wm + mi * 16 + fq * 4 + r;
        part[(size_t)j * B_ROWS + gm] = p;
      }
    }
  }
}

// ---------------------------------------------------------------------------
// Final: sum partials, sigmoid, broadcast to out [3, B, 9]. 1 thread/row.
// ---------------------------------------------------------------------------
__global__ __launch_bounds__(256) void final_out(
    const float* __restrict__ part,
    const float* __restrict__ bc2, const float* __restrict__ bt2,
    const float* __restrict__ bk2, float* __restrict__ out) {
  const int row = blockIdx.x * 256 + threadIdx.x;
  float sc = 0.f, st = 0.f, sk = 0.f;
#pragma unroll
  for (int j = 0; j < 8; ++j)  sc += part[(size_t)j * B_ROWS + row];
#pragma unroll
  for (int j = 8; j < 16; ++j) st += part[(size_t)j * B_ROWS + row];
#pragma unroll
  for (int j = 16; j < 32; ++j) sk += part[(size_t)j * B_ROWS + row];
  const float cv = 1.f / (1.f + expf(-(sc + bc2[0])));
  const float tv = 1.f / (1.f + expf(-(st + bt2[0])));
  const float kv = 1.f / (1.f + expf(-(sk + bk2[0])));
  float* o0 = out + (size_t)row * N_AG;
  float* o1 = out + (size_t)(B_ROWS + row) * N_AG;
  float* o2 = out + (size_t)(2 * B_ROWS + row) * N_AG;
#pragma unroll
  for (int a = 0; a < N_AG; ++a) { o0[a] = cv; o1[a] = tv; o2[a] = kv; }
}

// ---------------------------------------------------------------------------
extern "C" void kernel_launch(void* const* d_in, const int* in_sizes, int n_in,
                              void* d_out, int out_size, void* d_ws, size_t ws_size,
                              hipStream_t stream) {
  const float* obs = (const float*)d_in[0];
  // d_in[1] agent_positions: unused (outputs don't depend on it)
  const float* W1  = (const float*)d_in[2];
  const float* b1  = (const float*)d_in[3];
  const float* W2  = (const float*)d_in[4];
  const float* b2  = (const float*)d_in[5];
  const float* Wc1 = (const float*)d_in[6];
  const float* bc1 = (const float*)d_in[7];
  const float* Wc2 = (const float*)d_in[8];
  const float* bc2 = (const float*)d_in[9];
  const float* Wt1 = (const float*)d_in[10];
  const float* bt1 = (const float*)d_in[11];
  const float* Wt2 = (const float*)d_in[12];
  const float* bt2 = (const float*)d_in[13];
  const float* Wk1 = (const float*)d_in[14];
  const float* bk1 = (const float*)d_in[15];
  const float* Wk2 = (const float*)d_in[16];
  const float* bk2 = (const float*)d_in[17];
  float* out = (float*)d_out;

  // Workspace layout. PART aliases obs_bf (disjoint lifetimes).
  char* ws = (char*)d_ws;
  unsigned short* obs_bf  = (unsigned short*)(ws + 0);         // 16 MB
  float*          PART    = (float*)(ws + 0);                  // 2 MB (alias)
  unsigned short* W1T     = (unsigned short*)(ws + 16777216);  // 1 MB  [1024,512]
  unsigned short* W2T     = (unsigned short*)(ws + 17825792);  // 2 MB  [1024,1024]
  unsigned short* WH      = (unsigned short*)(ws + 19922944);  // 4 MB  [2048,1024]
  float*          bias2048= (float*)(ws + 24117248);           // 8 KB
  float*          w2cat   = (float*)(ws + 24125440);           // 8 KB
  unsigned short* G1      = (unsigned short*)(ws + 24330240);  // 32 MB
  unsigned short* G       = (unsigned short*)(ws + 57884672);  // 32 MB

  prep_all<<<7688, 256, 0, stream>>>(obs, W1, W2, Wc1, Wt1, Wk1,
                                     bc1, bt1, bk1, Wc2, Wt2, Wk2,
                                     obs_bf, W1T, W2T, WH, bias2048, w2cat);

  gemm_bias_relu<512><<<dim3(128, 8), 256, 0, stream>>>(obs_bf, W1T, b1, G1, B_ROWS, 1024);
  gemm_bias_relu<1024><<<dim3(128, 8), 256, 0, stream>>>(G1, W2T, b2, G, B_ROWS, 1024);

  gemm_heads_fused<1024><<<dim3(128, 16), 256, 0, stream>>>(G, WH, bias2048, w2cat, PART,
                                                            B_ROWS, 2048);

  final_out<<<B_ROWS / 256, 256, 0, stream>>>(PART, bc2, bt2, bk2, out);
}

// Round 8
// 278.472 us; speedup vs baseline: 39.1747x; 1.0574x over previous
//
#include <hip/hip_runtime.h>
#include <hip/hip_bf16.h>

// Problem constants
#define B_ROWS 16384
#define OBS_D  512
#define H_D    1024
#define N_AG   9

typedef __attribute__((ext_vector_type(8))) short short8;
typedef __attribute__((ext_vector_type(4))) float floatx4;

__device__ __forceinline__ unsigned short f_to_bf_raw(float f) {
  union { float f; unsigned u; } c; c.f = f;
  unsigned u = c.u;
  u = u + 0x7FFF + ((u >> 16) & 1);   // round-to-nearest-even
  return (unsigned short)(u >> 16);
}

// Fragment-major weight layout: element (n,k) of B^T lives at
//   frag_tile = (n>>4)*KT + (k>>5)        (KT = K/32)
//   lane      = (n&15) | (((k>>3)&3)<<4)  (MFMA 16x16x32 B-operand lane)
//   j         = k&7                        (element within lane's 16B)
// offset (bf16 units) = (frag_tile*64 + lane)*8 + j
// -> a wave's B-frag load is base + lane*16: one coalesced 1KB line.
__device__ __forceinline__ size_t frag_off(int n, int k, int KT) {
  const int ft = (n >> 4) * KT + (k >> 5);
  const int ln = (n & 15) | (((k >> 3) & 3) << 4);
  return ((size_t)ft * 64 + ln) * 8 + (k & 7);
}

// ---------------------------------------------------------------------------
// Mega-prep: obs cast, W1f/W2f/WHf (frag-major weights, WH = [Wc1|Wt1|Wk1fold]),
// bias2048/w2cat concat. Branch is block-uniform.
// Grid: [0,4096) obs | [4096,4608) W1f | [4608,5632) W2f |
//       [5632,7680) WHf | [7680,7688) vecs
// ---------------------------------------------------------------------------
__global__ __launch_bounds__(256) void prep_all(
    const float* __restrict__ obs,
    const float* __restrict__ W1, const float* __restrict__ W2,
    const float* __restrict__ Wc1, const float* __restrict__ Wt1,
    const float* __restrict__ Wk1,
    const float* __restrict__ bc1, const float* __restrict__ bt1,
    const float* __restrict__ bk1,
    const float* __restrict__ Wc2, const float* __restrict__ Wt2,
    const float* __restrict__ Wk2,
    unsigned short* __restrict__ obs_bf,
    unsigned short* __restrict__ W1f, unsigned short* __restrict__ W2f,
    unsigned short* __restrict__ WHf,
    float* __restrict__ bias2048, float* __restrict__ w2cat) {
  __shared__ float t[32][33];
  const int bx  = blockIdx.x;
  const int tid = threadIdx.x;

  if (bx < 4096) {                       // obs fp32 -> bf16, 8 elems/thread
    int i = (bx * 256 + tid) * 8;
    float4 a = *(const float4*)(obs + i);
    float4 b = *(const float4*)(obs + i + 4);
    short8 o;
    o[0] = (short)f_to_bf_raw(a.x); o[1] = (short)f_to_bf_raw(a.y);
    o[2] = (short)f_to_bf_raw(a.z); o[3] = (short)f_to_bf_raw(a.w);
    o[4] = (short)f_to_bf_raw(b.x); o[5] = (short)f_to_bf_raw(b.y);
    o[6] = (short)f_to_bf_raw(b.z); o[7] = (short)f_to_bf_raw(b.w);
    *(short8*)(obs_bf + i) = o;
    return;
  }

  const int tx = tid & 31;
  const int ty = tid >> 5;   // 0..7

  if (bx < 4608) {                       // W1 [512,1024] -> W1f (K=512,KT=16)
    const int tt = bx - 4096;
    const int k0 = (tt & 15) * 32;
    const int n0 = (tt >> 4) * 32;
#pragma unroll
    for (int i = ty; i < 32; i += 8)
      t[i][tx] = W1[(size_t)(k0 + i) * 1024 + n0 + tx];
    __syncthreads();
#pragma unroll
    for (int i = ty; i < 32; i += 8)
      W1f[frag_off(n0 + i, k0 + tx, 16)] = f_to_bf_raw(t[tx][i]);
    return;
  }

  if (bx < 5632) {                       // W2 [1024,1024] -> W2f (K=1024,KT=32)
    const int tt = bx - 4608;
    const int k0 = (tt & 31) * 32;
    const int n0 = (tt >> 5) * 32;
#pragma unroll
    for (int i = ty; i < 32; i += 8)
      t[i][tx] = W2[(size_t)(k0 + i) * 1024 + n0 + tx];
    __syncthreads();
#pragma unroll
    for (int i = ty; i < 32; i += 8)
      W2f[frag_off(n0 + i, k0 + tx, 32)] = f_to_bf_raw(t[tx][i]);
    return;
  }

  if (bx < 7680) {                       // WHf [2048 n,1024 k] (KT=32)
    const int tt = bx - 5632;
    const int k0 = (tt & 31) * 32;
    const int n0 = (tt >> 5) * 32;       // region-uniform per block
#pragma unroll
    for (int i = ty; i < 32; i += 8) {
      const int n = n0 + tx;
      float v;
      if (n0 < 512)
        v = Wc1[(size_t)(k0 + i) * 512 + n];
      else if (n0 < 1024)
        v = Wt1[(size_t)(k0 + i) * 512 + (n - 512)];
      else
        v = Wk1[(size_t)(k0 + i) * 1024 + (n - 1024)]
          + Wk1[(size_t)(k0 + i + 1024) * 1024 + (n - 1024)];
      t[i][tx] = v;
    }
    __syncthreads();
#pragma unroll
    for (int i = ty; i < 32; i += 8)
      WHf[frag_off(n0 + i, k0 + tx, 32)] = f_to_bf_raw(t[tx][i]);
    return;
  }

  {                                      // bias2048 / w2cat
    int n = (bx - 7680) * 256 + tid;
    float b, w;
    if (n < 512)       { b = bc1[n];        w = Wc2[n]; }
    else if (n < 1024) { b = bt1[n - 512];  w = Wt2[n - 512]; }
    else               { b = bk1[n - 1024]; w = Wk2[n - 1024]; }
    bias2048[n] = b;
    w2cat[n] = w;
  }
}

// ===========================================================================
// GEMM core v7: 128x128 tile, BK=32, one barrier/iter.
//  - A: LDS double-buffer (2 x 8 KB) via global_load_lds, XOR-swizzled,
//    register-dbuf frags (v6 pipeline). LDS traffic per block-iter: 8 KB
//    write + 16 KB read (was 48 KB total with B staged -> LDS-bound, r7).
//  - B: NO LDS. Weights are frag-major in global (L2/L3-resident, <=4 MB);
//    a B-frag load is one coalesced 1 KB global_load_dwordx4 at
//    base + lane*16, register-double-buffered one iter ahead. The barrier's
//    vmcnt(0) drain covers it with a full compute phase of slack.
// K template constant -> nIter constexpr -> full unroll -> all Fa/Fb indices
// compile-time (round-6 lesson: runtime-indexed arrays demote to scratch).
// ===========================================================================
#define GLD_LDS(gp, lp)                                                        \
  __builtin_amdgcn_global_load_lds(                                            \
      (const __attribute__((address_space(1))) void*)(gp),                     \
      (__attribute__((address_space(3))) void*)(lp), 16, 0, 0)

#define GEMM_CORE_V7(ACC_DECL)                                                 \
  __shared__ __align__(16) unsigned short As[2][128 * 32];  /* 16 KB */        \
  const int tid  = threadIdx.x;                                                \
  const int lane = tid & 63;                                                   \
  const int wave = tid >> 6;                                                   \
  const int m0 = blockIdx.x * 128;                                             \
  const int n0 = blockIdx.y * 128;                                             \
  const int wm = (wave & 1) * 64;                                              \
  const int wn = (wave >> 1) * 64;                                             \
  const int fr = lane & 15;                                                    \
  const int fq = lane >> 4;                                                    \
  ACC_DECL;                                                                    \
  constexpr int KT = K >> 5;                                                   \
  constexpr int nIter = KT;                                                    \
  const size_t rowb = (size_t)K * 2;                                           \
  const int srow   = lane >> 2;                                                \
  const int schunk = (lane & 3) ^ ((srow >> 1) & 3);                           \
  const char* gA0 = (const char*)A + (size_t)(m0 + wave * 32 + srow) * rowb    \
                    + schunk * 16;                                             \
  const char* gA1 = gA0 + 16 * rowb;                                           \
  char* lA = (char*)&As[0][0] + (wave * 32) * 64 + lane * 16;                  \
  const char* gBf = (const char*)Bf                                            \
      + (((size_t)((n0 >> 4) + (wn >> 4)) * KT) * 64 + lane) * 16;             \
  const int fswz = (fr >> 1) & 3;                                              \
  const int fsA = (wm + fr) * 64 + ((fq ^ fswz) * 16);                         \
  short8 Fa[2][4], Fb[2][4];                                                   \
  /* prologue: A(0)->buf0; sync; A(1)->buf1; Fb(0) global; Fa(0) ds_read */    \
  GLD_LDS(gA0, lA); GLD_LDS(gA1, lA + 1024);                                   \
  gA0 += 64; gA1 += 64;                                                        \
  __syncthreads();                                                             \
  GLD_LDS(gA0, lA + 8192); GLD_LDS(gA1, lA + 9216);                            \
  gA0 += 64; gA1 += 64;                                                        \
  _Pragma("unroll")                                                            \
  for (int ni = 0; ni < 4; ++ni)                                               \
    Fb[0][ni] = *(const short8*)(gBf + (size_t)ni * (KT * 1024));              \
  _Pragma("unroll")                                                            \
  for (int mi = 0; mi < 4; ++mi)                                               \
    Fa[0][mi] = *(const short8*)((const char*)&As[0][0] + fsA + mi * 1024);    \
  _Pragma("unroll")                                                            \
  for (int k = 0; k < nIter; ++k) {      /* constexpr bound -> full unroll */  \
    const int cur = k & 1;               /* constant per unrolled body */      \
    __syncthreads();                                                           \
    if (k + 2 < nIter) {                                                       \
      char* dA = lA + cur * 8192;                                              \
      GLD_LDS(gA0, dA); GLD_LDS(gA1, dA + 1024);                               \
      gA0 += 64; gA1 += 64;                                                    \
    }                                                                          \
    if (k + 1 < nIter) {                                                       \
      _Pragma("unroll")                                                        \
      for (int ni = 0; ni < 4; ++ni)                                           \
        Fb[cur ^ 1][ni] =                                                      \
            *(const short8*)(gBf + ((size_t)ni * KT + (k + 1)) * 1024);        \
      const char* bAs = (const char*)&As[0][0] + (cur ^ 1) * 8192;             \
      _Pragma("unroll")                                                        \
      for (int mi = 0; mi < 4; ++mi)                                           \
        Fa[cur ^ 1][mi] = *(const short8*)(bAs + fsA + mi * 1024);             \
    }                                                                          \
    _Pragma("unroll")                                                          \
    for (int mi = 0; mi < 4; ++mi)                                             \
      _Pragma("unroll")                                                        \
      for (int ni = 0; ni < 4; ++ni)                                           \
        acc[mi][ni] = __builtin_amdgcn_mfma_f32_16x16x32_bf16(                 \
            Fa[cur][mi], Fb[cur][ni], acc[mi][ni], 0, 0, 0);                   \
  }

#define ACC_INIT                                                               \
  floatx4 acc[4][4];                                                           \
  _Pragma("unroll")                                                            \
  for (int i = 0; i < 4; ++i)                                                  \
    _Pragma("unroll")                                                          \
    for (int j = 0; j < 4; ++j) acc[i][j] = (floatx4){0.f, 0.f, 0.f, 0.f}

// ---------------------------------------------------------------------------
// GEMM: C = relu(A @ B^T + bias), bf16 out. Bf is frag-major. K template.
// ---------------------------------------------------------------------------
template <int K>
__global__ __launch_bounds__(256, 3) void gemm_bias_relu(
    const unsigned short* __restrict__ A,
    const unsigned short* __restrict__ Bf,
    const float* __restrict__ bias,
    unsigned short* __restrict__ C,
    int M, int N) {
  GEMM_CORE_V7(ACC_INIT)

  // Epilogue: C/D layout col=lane&15, row=(lane>>4)*4+reg
#pragma unroll
  for (int ni = 0; ni < 4; ++ni) {
    const int gn = n0 + wn + ni * 16 + fr;
    const float bv = bias[gn];
#pragma unroll
    for (int mi = 0; mi < 4; ++mi) {
#pragma unroll
      for (int r = 0; r < 4; ++r) {
        const int gm = m0 + wm + mi * 16 + fq * 4 + r;
        float v = acc[mi][ni][r] + bv;
        v = v > 0.f ? v : 0.f;
        C[(size_t)gm * N + gn] = f_to_bf_raw(v);
      }
    }
  }
}

// ---------------------------------------------------------------------------
// Fused heads GEMM: relu(G @ WH^T + bias2048) dotted with w2cat in-register,
// non-atomic partials part[j][row], j = blockIdx.y*2 + wave_half in [0,32).
// j 0..7 coverage, 8..15 tracking, 16..31 cooperation.
// ---------------------------------------------------------------------------
template <int K>
__global__ __launch_bounds__(256, 3) void gemm_heads_fused(
    const unsigned short* __restrict__ A,    // G [B,1024]
    const unsigned short* __restrict__ Bf,   // WHf frag-major [2048,1024]
    const float* __restrict__ bias,          // bias2048
    const float* __restrict__ w2,            // w2cat
    float* __restrict__ part,                // [32][B_ROWS]
    int M, int N) {
  GEMM_CORE_V7(ACC_INIT)

  const int j = blockIdx.y * 2 + (wave >> 1);
  float w2v[4], bv[4];
#pragma unroll
  for (int ni = 0; ni < 4; ++ni) {
    const int gn = n0 + wn + ni * 16 + fr;
    w2v[ni] = w2[gn];
    bv[ni]  = bias[gn];
  }
#pragma unroll
  for (int mi = 0; mi < 4; ++mi) {
#pragma unroll
    for (int r = 0; r < 4; ++r) {
      float p = 0.f;
#pragma unroll
      for (int ni = 0; ni < 4; ++ni) {
        float v = acc[mi][ni][r] + bv[ni];
        v = v > 0.f ? v : 0.f;
        p += v * w2v[ni];
      }
      p += __shfl_xor(p, 1);
      p += __shfl_xor(p, 2);
      p += __shfl_xor(p, 4);
      p += __shfl_xor(p, 8);
      if (fr == 0) {
        const int gm = m0 + wm + mi * 16 + fq * 4 + r;
        part[(size_t)j * B_ROWS + gm] = p;
      }
    }
  }
}

// ---------------------------------------------------------------------------
// Final: sum partials, sigmoid, broadcast to out [3, B, 9]. 1 thread/row.
// ---------------------------------------------------------------------------
__global__ __launch_bounds__(256) void final_out(
    const float* __restrict__ part,
    const float* __restrict__ bc2, const float* __restrict__ bt2,
    const float* __restrict__ bk2, float* __restrict__ out) {
  const int row = blockIdx.x * 256 + threadIdx.x;
  float sc = 0.f, st = 0.f, sk = 0.f;
#pragma unroll
  for (int j = 0; j < 8; ++j)  sc += part[(size_t)j * B_ROWS + row];
#pragma unroll
  for (int j = 8; j < 16; ++j) st += part[(size_t)j * B_ROWS + row];
#pragma unroll
  for (int j = 16; j < 32; ++j) sk += part[(size_t)j * B_ROWS + row];
  const float cv = 1.f / (1.f + expf(-(sc + bc2[0])));
  const float tv = 1.f / (1.f + expf(-(st + bt2[0])));
  const float kv = 1.f / (1.f + expf(-(sk + bk2[0])));
  float* o0 = out + (size_t)row * N_AG;
  float* o1 = out + (size_t)(B_ROWS + row) * N_AG;
  float* o2 = out + (size_t)(2 * B_ROWS + row) * N_AG;
#pragma unroll
  for (int a = 0; a < N_AG; ++a) { o0[a] = cv; o1[a] = tv; o2[a] = kv; }
}

// ---------------------------------------------------------------------------
extern "C" void kernel_launch(void* const* d_in, const int* in_sizes, int n_in,
                              void* d_out, int out_size, void* d_ws, size_t ws_size,
                              hipStream_t stream) {
  const float* obs = (const float*)d_in[0];
  // d_in[1] agent_positions: unused (outputs don't depend on it)
  const float* W1  = (const float*)d_in[2];
  const float* b1  = (const float*)d_in[3];
  const float* W2  = (const float*)d_in[4];
  const float* b2  = (const float*)d_in[5];
  const float* Wc1 = (const float*)d_in[6];
  const float* bc1 = (const float*)d_in[7];
  const float* Wc2 = (const float*)d_in[8];
  const float* bc2 = (const float*)d_in[9];
  const float* Wt1 = (const float*)d_in[10];
  const float* bt1 = (const float*)d_in[11];
  const float* Wt2 = (const float*)d_in[12];
  const float* bt2 = (const float*)d_in[13];
  const float* Wk1 = (const float*)d_in[14];
  const float* bk1 = (const float*)d_in[15];
  const float* Wk2 = (const float*)d_in[16];
  const float* bk2 = (const float*)d_in[17];
  float* out = (float*)d_out;

  // Workspace layout. PART aliases obs_bf (disjoint lifetimes).
  char* ws = (char*)d_ws;
  unsigned short* obs_bf  = (unsigned short*)(ws + 0);         // 16 MB
  float*          PART    = (float*)(ws + 0);                  // 2 MB (alias)
  unsigned short* W1f     = (unsigned short*)(ws + 16777216);  // 1 MB  frag-major
  unsigned short* W2f     = (unsigned short*)(ws + 17825792);  // 2 MB  frag-major
  unsigned short* WHf     = (unsigned short*)(ws + 19922944);  // 4 MB  frag-major
  float*          bias2048= (float*)(ws + 24117248);           // 8 KB
  float*          w2cat   = (float*)(ws + 24125440);           // 8 KB
  unsigned short* G1      = (unsigned short*)(ws + 24330240);  // 32 MB
  unsigned short* G       = (unsigned short*)(ws + 57884672);  // 32 MB

  prep_all<<<7688, 256, 0, stream>>>(obs, W1, W2, Wc1, Wt1, Wk1,
                                     bc1, bt1, bk1, Wc2, Wt2, Wk2,
                                     obs_bf, W1f, W2f, WHf, bias2048, w2cat);

  gemm_bias_relu<512><<<dim3(128, 8), 256, 0, stream>>>(obs_bf, W1f, b1, G1, B_ROWS, 1024);
  gemm_bias_relu<1024><<<dim3(128, 8), 256, 0, stream>>>(G1, W2f, b2, G, B_ROWS, 1024);

  gemm_heads_fused<1024><<<dim3(128, 16), 256, 0, stream>>>(G, WHf, bias2048, w2cat, PART,
                                                            B_ROWS, 2048);

  final_out<<<B_ROWS / 256, 256, 0, stream>>>(PART, bc2, bt2, bk2, out);
}